// Round 7
// baseline (259.163 us; speedup 1.0000x reference)
//
#include <hip/hip_runtime.h>
#include <cstdint>
#include <cstddef>

#define NN 100000
#define NE 1600000
#define DD 64
#define NG 64

#define EPB 4096
#define NBLK ((NE + EPB - 1) / EPB)      // 391
#define NBUCK ((NN + 511) / 512)         // 196
#define BCAP 10240
#define NTILE (NN / 16)                  // 6250 (NN % 16 == 0)
#define NBF ((NTILE + 1) / 2)            // 3125 blocks, 2 tiles (4 half-tiles) each

typedef unsigned short u16;
typedef unsigned int u32;
typedef unsigned char u8;
typedef short short8 __attribute__((ext_vector_type(8)));
typedef float f32x4 __attribute__((ext_vector_type(4)));

__device__ __forceinline__ float bf2f(u16 h) {
    u32 u = ((u32)h) << 16;
    return __builtin_bit_cast(float, u);
}
__device__ __forceinline__ u16 f2bf(float f) {
    u32 u = __builtin_bit_cast(u32, f);
    u += 0x7fffu + ((u >> 16) & 1u);
    return (u16)(u >> 16);
}

// ---------------- CSR build: bucket partition, all-coalesced writes --------
__global__ void __launch_bounds__(256) k_hist(const int* __restrict__ dst,
                                              int* __restrict__ hist) {
    __shared__ int h[NBUCK];
    for (int i = threadIdx.x; i < NBUCK; i += 256) h[i] = 0;
    __syncthreads();
    const int base = blockIdx.x * EPB;
    const int end = (base + EPB < NE) ? base + EPB : NE;
    for (int i = base + threadIdx.x; i < end; i += 256)
        atomicAdd(&h[dst[i] >> 9], 1);
    __syncthreads();
    for (int i = threadIdx.x; i < NBUCK; i += 256)
        hist[i * NBLK + blockIdx.x] = h[i];
}

__global__ void __launch_bounds__(512) k_rowscan(int* __restrict__ hist,
                                                 int* __restrict__ btot) {
    __shared__ int s[2][512];
    const int b = blockIdx.x;
    const int t = threadIdx.x;
    int v = (t < NBLK) ? hist[b * NBLK + t] : 0;
    s[0][t] = v;
    __syncthreads();
    int sel = 0;
    for (int off = 1; off < 512; off <<= 1) {
        int x = s[sel][t];
        if (t >= off) x += s[sel][t - off];
        s[sel ^ 1][t] = x;
        __syncthreads();
        sel ^= 1;
    }
    if (t < NBLK) hist[b * NBLK + t] = s[sel][t] - v;
    if (t == 511) btot[b] = s[sel][511];
}

__global__ void __launch_bounds__(256) k_btscan(int* __restrict__ btot) {
    __shared__ int s[2][256];
    const int t = threadIdx.x;
    int v = (t < NBUCK) ? btot[t] : 0;
    s[0][t] = v;
    __syncthreads();
    int sel = 0;
    for (int off = 1; off < 256; off <<= 1) {
        int x = s[sel][t];
        if (t >= off) x += s[sel][t - off];
        s[sel ^ 1][t] = x;
        __syncthreads();
        sel ^= 1;
    }
    if (t < NBUCK) btot[t] = s[sel][t] - v;
    if (t == 0) btot[NBUCK] = NE;
}

__global__ void __launch_bounds__(256) k_part(const int* __restrict__ src,
                                              const int* __restrict__ dst,
                                              const int* __restrict__ excl,
                                              const int* __restrict__ btot,
                                              u32* __restrict__ part) {
    __shared__ int cnt[NBUCK];
    __shared__ int diff[NBUCK];
    __shared__ int cur[NBUCK];
    __shared__ int sc[2][256];
    __shared__ u32 pk[EPB];
    __shared__ u8  bk[EPB];
    const int t = threadIdx.x;
    const int blk = blockIdx.x;
    const int base = blk * EPB;
    const int n = ((base + EPB < NE) ? EPB : NE - base);
    for (int i = t; i < NBUCK; i += 256) cnt[i] = 0;
    __syncthreads();

    int myb[EPB / 256];
    u32 mypk[EPB / 256];
#pragma unroll
    for (int j = 0; j < EPB / 256; ++j) {
        int i = t + j * 256;
        bool ok = i < n;
        int d = ok ? dst[base + i] : 0;
        int s2 = ok ? src[base + i] : 0;
        int b = d >> 9;
        myb[j] = b;
        mypk[j] = ((u32)(d & 511) << 17) | (u32)s2;
        if (ok) atomicAdd(&cnt[b], 1);
    }
    __syncthreads();
    int v = (t < NBUCK) ? cnt[t] : 0;
    sc[0][t] = v;
    __syncthreads();
    int sel = 0;
    for (int off = 1; off < 256; off <<= 1) {
        int x = sc[sel][t];
        if (t >= off) x += sc[sel][t - off];
        sc[sel ^ 1][t] = x;
        __syncthreads();
        sel ^= 1;
    }
    if (t < NBUCK) {
        int e = sc[sel][t] - v;
        cur[t] = e;
        diff[t] = excl[t * NBLK + blk] + btot[t] - e;
    }
    __syncthreads();
#pragma unroll
    for (int j = 0; j < EPB / 256; ++j) {
        int i = t + j * 256;
        if (i < n) {
            int pos = atomicAdd(&cur[myb[j]], 1);
            pk[pos] = mypk[j];
            bk[pos] = (u8)myb[j];
        }
    }
    __syncthreads();
    for (int p = t; p < n; p += 256)
        part[diff[bk[p]] + p] = pk[p];
}

__global__ void __launch_bounds__(512) k_bucket(const u32* __restrict__ part,
                                                const int* __restrict__ btot,
                                                int* __restrict__ row_off,
                                                int* __restrict__ srcs,
                                                float* __restrict__ deg_inv) {
    __shared__ int cnt[512];
    __shared__ int cur[512];
    __shared__ int sc[2][512];
    __shared__ int lsrc[BCAP];
    const int b = blockIdx.x;
    const int t = threadIdx.x;
    const int base = btot[b];
    const int endp = btot[b + 1];
    const int n = endp - base;
    cnt[t] = 0;
    __syncthreads();
    for (int i = t; i < n; i += 512)
        atomicAdd(&cnt[part[base + i] >> 17], 1);
    __syncthreads();
    int v = cnt[t];
    sc[0][t] = v;
    __syncthreads();
    int sel = 0;
    for (int off = 1; off < 512; off <<= 1) {
        int x = sc[sel][t];
        if (t >= off) x += sc[sel][t - off];
        sc[sel ^ 1][t] = x;
        __syncthreads();
        sel ^= 1;
    }
    const int el = sc[sel][t] - v;
    const int g = b * 512 + t;
    if (g < NN) {
        row_off[g] = base + el;
        deg_inv[g] = (v > 0) ? 1.0f / (float)v : 0.0f;
    }
    if (b == NBUCK - 1 && t == 0) row_off[NN] = NE;
    cur[t] = el;
    __syncthreads();
    for (int i = t; i < n; i += 512) {
        u32 p = part[base + i];
        int pos = atomicAdd(&cur[p >> 17], 1);
        int s2 = (int)(p & 0x1FFFFu);
        if (pos < BCAP) lsrc[pos] = s2;
        else srcs[base + pos] = s2;
    }
    __syncthreads();
    const int lim = (n < BCAP) ? n : BCAP;
    for (int i = t; i < lim; i += 512)
        srcs[base + i] = lsrc[i];
}

// ---------------- fp32 -> bf16: features + all 6 weight matrices -----------
__global__ void k_cvtall(const float* __restrict__ x, u16* __restrict__ xb,
                         const float* __restrict__ w0, const float* __restrict__ w1,
                         const float* __restrict__ w2, const float* __restrict__ w3,
                         const float* __restrict__ w4, const float* __restrict__ w5,
                         u16* __restrict__ wbuf) {
    int i = blockIdx.x * blockDim.x + threadIdx.x;
    int stride = gridDim.x * blockDim.x;
    const int total = NN * DD / 4;   // feature quads
    const int wt4 = 6 * 4096 / 4;    // weight quads
    for (; i < total + wt4; i += stride) {
        const float* p;
        uint2* dst;
        if (i < total) {
            p = &x[(size_t)i * 4];
            dst = &((uint2*)xb)[i];
        } else {
            int k = (i - total) * 4;
            int m = k >> 12;
            const float* W = (m == 0) ? w0 : (m == 1) ? w1 : (m == 2) ? w2
                           : (m == 3) ? w3 : (m == 4) ? w4 : w5;
            p = &W[k & 4095];
            dst = &((uint2*)wbuf)[i - total];
        }
        float4 v = *(const float4*)p;
        uint2 pk;
        pk.x = (u32)f2bf(v.x) | ((u32)f2bf(v.y) << 16);
        pk.y = (u32)f2bf(v.z) | ((u32)f2bf(v.w) << 16);
        *dst = pk;
    }
}

// ---------------- fused layer: gather (mean) + dual GEMM + bias (+relu) ----
// Wave gathers 8 nodes (12500 waves -> saturates 32 waves/CU). A wave PAIR
// shares one 16-row swizzled LDS tile; after __syncthreads each wave runs
// half the MFMA tile (2 of 4 column-quadrants).
__global__ void __launch_bounds__(256) k_fused(
    const u16* __restrict__ hin, u16* __restrict__ hout,
    const u16* __restrict__ wb,   // [2][4096] bf16: Wl, Wr
    const float* __restrict__ bl,
    const int* __restrict__ row_off, const int* __restrict__ srcs,
    const float* __restrict__ deg_inv, int relu) {
    __shared__ int ids[4][64];
    __shared__ __align__(16) u8 aggT[2][2048];   // per wave-pair: 16 rows x 128B
    const int tid   = threadIdx.x;
    const int lane  = tid & 63;
    const int wid   = tid >> 6;
    const int half  = lane >> 5;
    const int fp    = (lane & 31) * 2;
    const int pairi = wid >> 1;
    const int tile  = blockIdx.x * 2 + pairi;
    const int hbase = (wid & 1) * 8;             // this wave's rows in the tile
    const int n0    = tile * 16;
    const int ng    = n0 + hbase;

    // ---- gather phase: 8 nodes, wave-private ----
    int beg = row_off[ng], end = row_off[ng + 1];
    int myid = (beg + lane < end) ? srcs[beg + lane] : 0;

#define PAIR(J, SLO, SHI) { \
        int _id = ids[wid][(J) + half]; \
        u32 _v = *(const u32*)&hin[(size_t)_id * DD + fp]; \
        SLO += __builtin_bit_cast(float, _v << 16); \
        SHI += __builtin_bit_cast(float, _v & 0xffff0000u); }

    for (int j = 0; j < 8; ++j) {
        ids[wid][lane] = myid;
        __builtin_amdgcn_wave_barrier();
        // prefetch next node's ids
        int beg2 = 0, end2 = 0;
        if (j < 7) { beg2 = row_off[ng + j + 1]; end2 = row_off[ng + j + 2]; }
        myid = (beg2 + lane < end2) ? srcs[beg2 + lane] : 0;
        const float dinv = deg_inv[ng + j];

        int deg = end - beg;
        int cnt = deg < 64 ? deg : 64;
        float s0 = 0.f, s1 = 0.f, t0 = 0.f, t1 = 0.f;
        float u0 = 0.f, u1 = 0.f, w0 = 0.f, w1 = 0.f;
        int jq = 0;
        for (; jq + 16 <= cnt; jq += 16) {
            PAIR(jq + 0,  s0, s1)
            PAIR(jq + 2,  t0, t1)
            PAIR(jq + 4,  u0, u1)
            PAIR(jq + 6,  w0, w1)
            PAIR(jq + 8,  s0, s1)
            PAIR(jq + 10, t0, t1)
            PAIR(jq + 12, u0, u1)
            PAIR(jq + 14, w0, w1)
        }
        for (; jq + 2 <= cnt; jq += 2) PAIR(jq, s0, s1)
        if (jq < cnt) {
            int _id = ids[wid][jq];
            if (half == 0) {
                u32 _v = *(const u32*)&hin[(size_t)_id * DD + fp];
                s0 += __builtin_bit_cast(float, _v << 16);
                s1 += __builtin_bit_cast(float, _v & 0xffff0000u);
            }
        }
        for (int base2 = 64; base2 < deg; base2 += 64) {   // rare deg>64
            __builtin_amdgcn_wave_barrier();
            int m = deg - base2; if (m > 64) m = 64;
            if (lane < m) ids[wid][lane] = srcs[beg + base2 + lane];
            __builtin_amdgcn_wave_barrier();
            int j2 = 0;
            for (; j2 + 2 <= m; j2 += 2) PAIR(j2, s0, s1)
            if (j2 < m) {
                int _id = ids[wid][j2];
                if (half == 0) {
                    u32 _v = *(const u32*)&hin[(size_t)_id * DD + fp];
                    s0 += __builtin_bit_cast(float, _v << 16);
                    s1 += __builtin_bit_cast(float, _v & 0xffff0000u);
                }
            }
        }
        float aLo = (s0 + t0) + (u0 + w0);
        float aHi = (s1 + t1) + (u1 + w1);
        aLo += __shfl_xor(aLo, 32);
        aHi += __shfl_xor(aHi, 32);
        aLo *= dinv; aHi *= dinv;
        if (half == 0) {
            u32 pk = (u32)f2bf(aLo) | ((u32)f2bf(aHi) << 16);
            const int hr = hbase + j;
            *(u32*)&aggT[pairi][hr * 128 + ((fp * 2) ^ ((hr & 7) << 4))] = pk;
        }
        beg = beg2; end = end2;
        __builtin_amdgcn_wave_barrier();
    }
#undef PAIR

    __syncthreads();                 // both halves of each pair's tile done
    asm volatile("" ::: "memory");   // keep weight loads out of gather phase

    // ---- MFMA phase: this wave does 2 of the 4 column-quadrants ----
    const int r = lane & 15, g = lane >> 4;
    const int ct0 = (wid & 1) * 2;
    f32x4 acc[2] = {};
#pragma unroll
    for (int kc = 0; kc < 2; ++kc) {
        const int cb = kc * 64 + g * 16;
        short8 aA = *(const short8*)&aggT[pairi][r * 128 + (cb ^ ((r & 7) << 4))];
        short8 aH = *(const short8*)&hin[(size_t)(n0 + r) * DD + kc * 32 + g * 8];
#pragma unroll
        for (int c = 0; c < 2; ++c) {
            const int wrow = ((ct0 + c) * 16 + r) * DD + kc * 32 + g * 8;
            short8 bA = *(const short8*)&wb[wrow];
            short8 bH = *(const short8*)&wb[4096 + wrow];
            acc[c] = __builtin_amdgcn_mfma_f32_16x16x32_bf16(aA, bA, acc[c], 0, 0, 0);
            acc[c] = __builtin_amdgcn_mfma_f32_16x16x32_bf16(aH, bH, acc[c], 0, 0, 0);
        }
    }
#pragma unroll
    for (int c = 0; c < 2; ++c) {
        const int ct = ct0 + c;
        float bias = bl[ct * 16 + r];
#pragma unroll
        for (int e = 0; e < 4; ++e) {
            float v = acc[c][e] + bias;
            if (relu) v = fmaxf(v, 0.f);
            hout[(size_t)(n0 + g * 4 + e) * DD + ct * 16 + r] = f2bf(v);
        }
    }
}

// ---------------- graph readout ----------------
__global__ void k_reduce(const u16* __restrict__ h, const int* __restrict__ batch,
                         float* __restrict__ out) {
    const int lane = threadIdx.x & 63;
    const int wid  = threadIdx.x >> 6;
    const int gw   = blockIdx.x * 4 + wid;
    const int start = gw * 64;
    if (start >= NN) return;
    const int endn = (start + 64 < NN) ? start + 64 : NN;
    float acc = 0.f;
    int gcur = batch[start];
    for (int i = start; i < endn; ++i) {
        int g = batch[i];
        if (g != gcur) {
            atomicAdd(&out[gcur * DD + lane], acc);
            acc = 0.f;
            gcur = g;
        }
        acc += bf2f(h[(size_t)i * DD + lane]);
    }
    atomicAdd(&out[gcur * DD + lane], acc);
}

extern "C" void kernel_launch(void* const* d_in, const int* in_sizes, int n_in,
                              void* d_out, int out_size, void* d_ws, size_t ws_size,
                              hipStream_t stream) {
    const float* x     = (const float*)d_in[0];
    const int*   ei    = (const int*)d_in[1];
    const int*   batch = (const int*)d_in[2];
    const float* Wl[3] = {(const float*)d_in[3], (const float*)d_in[6], (const float*)d_in[9]};
    const float* bl[3] = {(const float*)d_in[4], (const float*)d_in[7], (const float*)d_in[10]};
    const float* Wr[3] = {(const float*)d_in[5], (const float*)d_in[8], (const float*)d_in[11]};
    float* out = (float*)d_out;

    char* ws = (char*)d_ws;
    size_t off = 0;
    auto alloc = [&](size_t bytes) -> void* {
        void* p = ws + off;
        off = (off + bytes + 255) & ~(size_t)255;
        return p;
    };
    int*   hist    = (int*)  alloc((size_t)NBUCK * NBLK * 4);
    int*   btot    = (int*)  alloc(((size_t)NBUCK + 1) * 4);
    float* deg_inv = (float*)alloc((size_t)NN * 4);
    int*   row_off = (int*)  alloc(((size_t)NN + 1) * 4);
    int*   srcs    = (int*)  alloc((size_t)NE * 4);
    u32*   part    = (u32*)  alloc((size_t)NE * 4);
    u16*   wbuf    = (u16*)  alloc((size_t)6 * 4096 * 2);
    u16*   xb      = (u16*)  alloc((size_t)NN * DD * 2);
    u16*   hAb     = (u16*)  alloc((size_t)NN * DD * 2);
    u16*   hBb     = (u16*)  alloc((size_t)NN * DD * 2);

    const int* e_src = ei;       // edge_index[0]
    const int* e_dst = ei + NE;  // edge_index[1]

    hipMemsetAsync(out, 0, (size_t)NG * DD * 4, stream);

    k_hist<<<NBLK, 256, 0, stream>>>(e_dst, hist);
    k_rowscan<<<NBUCK, 512, 0, stream>>>(hist, btot);
    k_btscan<<<1, 256, 0, stream>>>(btot);
    k_part<<<NBLK, 256, 0, stream>>>(e_src, e_dst, hist, btot, part);
    k_bucket<<<NBUCK, 512, 0, stream>>>(part, btot, row_off, srcs, deg_inv);
    k_cvtall<<<2048, 256, 0, stream>>>(x, xb, Wl[0], Wr[0], Wl[1], Wr[1], Wl[2], Wr[2], wbuf);

    k_fused<<<NBF, 256, 0, stream>>>(xb,  hAb, wbuf,            bl[0], row_off, srcs, deg_inv, 1);
    k_fused<<<NBF, 256, 0, stream>>>(hAb, hBb, wbuf + 1 * 8192, bl[1], row_off, srcs, deg_inv, 1);
    k_fused<<<NBF, 256, 0, stream>>>(hBb, hAb, wbuf + 2 * 8192, bl[2], row_off, srcs, deg_inv, 0);

    k_reduce<<<(NN / 64 + 4) / 4, 256, 0, stream>>>(hAb, batch, out);
}

// Round 8
// 205.148 us; speedup vs baseline: 1.2633x; 1.2633x over previous
//
#include <hip/hip_runtime.h>
#include <cstdint>
#include <cstddef>

#define NN 100000
#define NE 1600000
#define DD 64
#define NG 64

#define EPB 4096
#define NBLK ((NE + EPB - 1) / EPB)      // 391
#define NBUCK ((NN + 511) / 512)         // 196
#define BCAP 10240
#define NTILE (NN / 16)                  // 6250
#define NBT ((NTILE + 3) / 4)            // 1563 blocks, 4 independent waves each

typedef unsigned short u16;
typedef unsigned int u32;
typedef unsigned char u8;
typedef short short8 __attribute__((ext_vector_type(8)));
typedef float f32x4 __attribute__((ext_vector_type(4)));
typedef float f32x2 __attribute__((ext_vector_type(2)));

__device__ __forceinline__ float bf2f(u16 h) {
    u32 u = ((u32)h) << 16;
    return __builtin_bit_cast(float, u);
}
__device__ __forceinline__ u16 f2bf(float f) {
    u32 u = __builtin_bit_cast(u32, f);
    u += 0x7fffu + ((u >> 16) & 1u);
    return (u16)(u >> 16);
}

// ---------------- CSR build: bucket partition, all-coalesced writes --------
__global__ void __launch_bounds__(256) k_hist(const int* __restrict__ dst,
                                              int* __restrict__ hist) {
    __shared__ int h[NBUCK];
    for (int i = threadIdx.x; i < NBUCK; i += 256) h[i] = 0;
    __syncthreads();
    const int base = blockIdx.x * EPB;
    const int end = (base + EPB < NE) ? base + EPB : NE;
    for (int i = base + threadIdx.x; i < end; i += 256)
        atomicAdd(&h[dst[i] >> 9], 1);
    __syncthreads();
    for (int i = threadIdx.x; i < NBUCK; i += 256)
        hist[i * NBLK + blockIdx.x] = h[i];
}

__global__ void __launch_bounds__(512) k_rowscan(int* __restrict__ hist,
                                                 int* __restrict__ btot) {
    __shared__ int s[2][512];
    const int b = blockIdx.x;
    const int t = threadIdx.x;
    int v = (t < NBLK) ? hist[b * NBLK + t] : 0;
    s[0][t] = v;
    __syncthreads();
    int sel = 0;
    for (int off = 1; off < 512; off <<= 1) {
        int x = s[sel][t];
        if (t >= off) x += s[sel][t - off];
        s[sel ^ 1][t] = x;
        __syncthreads();
        sel ^= 1;
    }
    if (t < NBLK) hist[b * NBLK + t] = s[sel][t] - v;
    if (t == 511) btot[b] = s[sel][511];
}

__global__ void __launch_bounds__(256) k_btscan(int* __restrict__ btot) {
    __shared__ int s[2][256];
    const int t = threadIdx.x;
    int v = (t < NBUCK) ? btot[t] : 0;
    s[0][t] = v;
    __syncthreads();
    int sel = 0;
    for (int off = 1; off < 256; off <<= 1) {
        int x = s[sel][t];
        if (t >= off) x += s[sel][t - off];
        s[sel ^ 1][t] = x;
        __syncthreads();
        sel ^= 1;
    }
    if (t < NBUCK) btot[t] = s[sel][t] - v;
    if (t == 0) btot[NBUCK] = NE;
}

__global__ void __launch_bounds__(256) k_part(const int* __restrict__ src,
                                              const int* __restrict__ dst,
                                              const int* __restrict__ excl,
                                              const int* __restrict__ btot,
                                              u32* __restrict__ part) {
    __shared__ int cnt[NBUCK];
    __shared__ int diff[NBUCK];
    __shared__ int cur[NBUCK];
    __shared__ int sc[2][256];
    __shared__ u32 pk[EPB];
    __shared__ u8  bk[EPB];
    const int t = threadIdx.x;
    const int blk = blockIdx.x;
    const int base = blk * EPB;
    const int n = ((base + EPB < NE) ? EPB : NE - base);
    for (int i = t; i < NBUCK; i += 256) cnt[i] = 0;
    __syncthreads();

    int myb[EPB / 256];
    u32 mypk[EPB / 256];
#pragma unroll
    for (int j = 0; j < EPB / 256; ++j) {
        int i = t + j * 256;
        bool ok = i < n;
        int d = ok ? dst[base + i] : 0;
        int s2 = ok ? src[base + i] : 0;
        int b = d >> 9;
        myb[j] = b;
        mypk[j] = ((u32)(d & 511) << 17) | (u32)s2;
        if (ok) atomicAdd(&cnt[b], 1);
    }
    __syncthreads();
    int v = (t < NBUCK) ? cnt[t] : 0;
    sc[0][t] = v;
    __syncthreads();
    int sel = 0;
    for (int off = 1; off < 256; off <<= 1) {
        int x = sc[sel][t];
        if (t >= off) x += sc[sel][t - off];
        sc[sel ^ 1][t] = x;
        __syncthreads();
        sel ^= 1;
    }
    if (t < NBUCK) {
        int e = sc[sel][t] - v;
        cur[t] = e;
        diff[t] = excl[t * NBLK + blk] + btot[t] - e;
    }
    __syncthreads();
#pragma unroll
    for (int j = 0; j < EPB / 256; ++j) {
        int i = t + j * 256;
        if (i < n) {
            int pos = atomicAdd(&cur[myb[j]], 1);
            pk[pos] = mypk[j];
            bk[pos] = (u8)myb[j];
        }
    }
    __syncthreads();
    for (int p = t; p < n; p += 256)
        part[diff[bk[p]] + p] = pk[p];
}

__global__ void __launch_bounds__(512) k_bucket(const u32* __restrict__ part,
                                                const int* __restrict__ btot,
                                                int* __restrict__ row_off,
                                                int* __restrict__ srcs,
                                                float* __restrict__ deg_inv) {
    __shared__ int cnt[512];
    __shared__ int cur[512];
    __shared__ int sc[2][512];
    __shared__ int lsrc[BCAP];
    const int b = blockIdx.x;
    const int t = threadIdx.x;
    const int base = btot[b];
    const int endp = btot[b + 1];
    const int n = endp - base;
    cnt[t] = 0;
    __syncthreads();
    for (int i = t; i < n; i += 512)
        atomicAdd(&cnt[part[base + i] >> 17], 1);
    __syncthreads();
    int v = cnt[t];
    sc[0][t] = v;
    __syncthreads();
    int sel = 0;
    for (int off = 1; off < 512; off <<= 1) {
        int x = sc[sel][t];
        if (t >= off) x += sc[sel][t - off];
        sc[sel ^ 1][t] = x;
        __syncthreads();
        sel ^= 1;
    }
    const int el = sc[sel][t] - v;
    const int g = b * 512 + t;
    if (g < NN) {
        row_off[g] = base + el;
        deg_inv[g] = (v > 0) ? 1.0f / (float)v : 0.0f;
    }
    if (b == NBUCK - 1 && t == 0) row_off[NN] = NE;
    cur[t] = el;
    __syncthreads();
    for (int i = t; i < n; i += 512) {
        u32 p = part[base + i];
        int pos = atomicAdd(&cur[p >> 17], 1);
        int s2 = (int)(p & 0x1FFFFu);
        if (pos < BCAP) lsrc[pos] = s2;
        else srcs[base + pos] = s2;
    }
    __syncthreads();
    const int lim = (n < BCAP) ? n : BCAP;
    for (int i = t; i < lim; i += 512)
        srcs[base + i] = lsrc[i];
}

// ------- fp32 -> bf16 + fp8 (features), bf16 (weights), zero sentinels -----
__global__ void k_cvtall(const float* __restrict__ x, u16* __restrict__ xb,
                         u8* __restrict__ xb8, u8* __restrict__ hA8,
                         u8* __restrict__ hB8,
                         const float* __restrict__ w0, const float* __restrict__ w1,
                         const float* __restrict__ w2, const float* __restrict__ w3,
                         const float* __restrict__ w4, const float* __restrict__ w5,
                         u16* __restrict__ wbuf) {
    int i = blockIdx.x * blockDim.x + threadIdx.x;
    // zero the sentinel row (id = NN) of all three fp8 tables
    if (blockIdx.x == 0 && threadIdx.x < 48) {
        int wq = threadIdx.x & 15, wb_ = threadIdx.x >> 4;
        u8* tb = (wb_ == 0) ? xb8 : (wb_ == 1) ? hA8 : hB8;
        *(u32*)&tb[(size_t)NN * DD + wq * 4] = 0u;
    }
    int stride = gridDim.x * blockDim.x;
    const int total = NN * DD / 4;   // feature quads
    const int wt4 = 6 * 4096 / 4;    // weight quads
    for (; i < total + wt4; i += stride) {
        if (i < total) {
            float4 v = *(const float4*)&x[(size_t)i * 4];
            uint2 pk;
            pk.x = (u32)f2bf(v.x) | ((u32)f2bf(v.y) << 16);
            pk.y = (u32)f2bf(v.z) | ((u32)f2bf(v.w) << 16);
            ((uint2*)xb)[i] = pk;
            u32 lo = (u32)__builtin_amdgcn_cvt_pk_fp8_f32(v.x, v.y, 0, false);
            u32 q8 = (u32)__builtin_amdgcn_cvt_pk_fp8_f32(v.z, v.w, (int)lo, true);
            ((u32*)xb8)[i] = q8;
        } else {
            int k = (i - total) * 4;
            int m = k >> 12;
            const float* W = (m == 0) ? w0 : (m == 1) ? w1 : (m == 2) ? w2
                           : (m == 3) ? w3 : (m == 4) ? w4 : w5;
            float4 v = *(const float4*)&W[k & 4095];
            uint2 pk;
            pk.x = (u32)f2bf(v.x) | ((u32)f2bf(v.y) << 16);
            pk.y = (u32)f2bf(v.z) | ((u32)f2bf(v.w) << 16);
            ((uint2*)wbuf)[i - total] = pk;
        }
    }
}

// ---------------- fused layer: fp8 gather (mean) + dual bf16 GEMM ----------
// One INDEPENDENT wave per 16-node tile (R6 structure). Gather reads the fp8
// feature table: row = 64B, 4 rows per load instruction (lane quarters),
// sentinel row NN = zeros removes all tail guards. MFMA phase unchanged
// (agg via swizzled LDS transpose, x-term from bf16 table, bf16 weights from
// global/L1). Epilogue writes bf16 + fp8 copies of the layer output.
__global__ void __launch_bounds__(256) k_fused(
    const u16* __restrict__ hin, const u8* __restrict__ hin8,
    u16* __restrict__ hout, u8* __restrict__ hout8,
    const u16* __restrict__ wb,   // [2][4096] bf16: Wl, Wr
    const float* __restrict__ bl,
    const int* __restrict__ row_off, const int* __restrict__ srcs,
    const float* __restrict__ deg_inv, int relu) {
    __shared__ int ids[4][64];
    __shared__ __align__(16) u8 aggT[4][2048];   // 16 rows x 128B, swizzled
    const int tid  = threadIdx.x;
    const int lane = tid & 63;
    const int wid  = tid >> 6;
    const int q    = lane >> 4;        // row quarter 0..3
    const int fl4  = (lane & 15) * 4;  // fp8 feature base (4 per lane)
    const int tile = blockIdx.x * 4 + wid;
    if (tile >= NTILE) return;
    const int n0 = tile * 16;

    // ---- gather phase: 16 nodes, wave-private, fp8 quad loads ----
    int beg = row_off[n0], end = row_off[n0 + 1];
    int myid = (beg + lane < end) ? srcs[beg + lane] : NN;

#define QUAD(J, A01, A23) { \
        int _id = ids[wid][(J) + q]; \
        u32 _v = *(const u32*)&hin8[(size_t)_id * DD + fl4]; \
        A01 += __builtin_amdgcn_cvt_pk_f32_fp8(_v, false); \
        A23 += __builtin_amdgcn_cvt_pk_f32_fp8(_v, true); }

    for (int j = 0; j < 16; ++j) {
        ids[wid][lane] = myid;
        __builtin_amdgcn_wave_barrier();
        // prefetch next node's ids
        int beg2 = 0, end2 = 0;
        if (j < 15) { beg2 = row_off[n0 + j + 1]; end2 = row_off[n0 + j + 2]; }
        myid = (beg2 + lane < end2) ? srcs[beg2 + lane] : NN;
        const float dinv = deg_inv[n0 + j];

        int deg = end - beg;
        int cnt = deg < 64 ? deg : 64;
        f32x2 a01 = {0.f, 0.f}, a23 = {0.f, 0.f};
        f32x2 b01 = {0.f, 0.f}, b23 = {0.f, 0.f};
        for (int jq = 0; jq < cnt; jq += 16) {   // 16 rows (incl. sentinels)
            QUAD(jq + 0,  a01, a23)
            QUAD(jq + 4,  b01, b23)
            QUAD(jq + 8,  a01, a23)
            QUAD(jq + 12, b01, b23)
        }
        for (int base2 = 64; base2 < deg; base2 += 64) {   // rare deg>64
            __builtin_amdgcn_wave_barrier();
            ids[wid][lane] = (beg + base2 + lane < end) ? srcs[beg + base2 + lane] : NN;
            __builtin_amdgcn_wave_barrier();
            int m = deg - base2; if (m > 64) m = 64;
            for (int jq = 0; jq < m; jq += 16) {
                QUAD(jq + 0,  a01, a23)
                QUAD(jq + 4,  b01, b23)
                QUAD(jq + 8,  a01, a23)
                QUAD(jq + 12, b01, b23)
            }
        }
        a01 += b01; a23 += b23;
        float s0 = a01.x, s1 = a01.y, s2 = a23.x, s3 = a23.y;
        s0 += __shfl_xor(s0, 32); s1 += __shfl_xor(s1, 32);
        s2 += __shfl_xor(s2, 32); s3 += __shfl_xor(s3, 32);
        s0 += __shfl_xor(s0, 16); s1 += __shfl_xor(s1, 16);
        s2 += __shfl_xor(s2, 16); s3 += __shfl_xor(s3, 16);
        s0 *= dinv; s1 *= dinv; s2 *= dinv; s3 *= dinv;
        if (lane < 16) {
            uint2 pk;
            pk.x = (u32)f2bf(s0) | ((u32)f2bf(s1) << 16);
            pk.y = (u32)f2bf(s2) | ((u32)f2bf(s3) << 16);
            *(uint2*)&aggT[wid][j * 128 + ((fl4 * 2) ^ ((j & 7) << 4))] = pk;
        }
        beg = beg2; end = end2;
        __builtin_amdgcn_wave_barrier();
    }
#undef QUAD

    asm volatile("" ::: "memory");   // keep weight loads out of gather phase

    // ---- MFMA phase: wave's own 16-node tile ----
    const int r = lane & 15, g = lane >> 4;
    f32x4 acc[4] = {};
#pragma unroll
    for (int kc = 0; kc < 2; ++kc) {
        const int cb = kc * 64 + g * 16;
        short8 aA = *(const short8*)&aggT[wid][r * 128 + (cb ^ ((r & 7) << 4))];
        short8 aH = *(const short8*)&hin[(size_t)(n0 + r) * DD + kc * 32 + g * 8];
#pragma unroll
        for (int ct = 0; ct < 4; ++ct) {
            const int wrow = (ct * 16 + r) * DD + kc * 32 + g * 8;
            short8 bA = *(const short8*)&wb[wrow];
            short8 bH = *(const short8*)&wb[4096 + wrow];
            acc[ct] = __builtin_amdgcn_mfma_f32_16x16x32_bf16(aA, bA, acc[ct], 0, 0, 0);
            acc[ct] = __builtin_amdgcn_mfma_f32_16x16x32_bf16(aH, bH, acc[ct], 0, 0, 0);
        }
    }
#pragma unroll
    for (int ct = 0; ct < 4; ++ct) {
        float bias = bl[ct * 16 + r];
#pragma unroll
        for (int e = 0; e < 4; ++e) {
            float v = acc[ct][e] + bias;
            if (relu) v = fmaxf(v, 0.f);
            const size_t node = (size_t)(n0 + g * 4 + e);
            hout[node * DD + ct * 16 + r] = f2bf(v);
            hout8[node * DD + ct * 16 + r] =
                (u8)((u32)__builtin_amdgcn_cvt_pk_fp8_f32(v, v, 0, false) & 0xffu);
        }
    }
}

// ---------------- graph readout ----------------
__global__ void k_reduce(const u16* __restrict__ h, const int* __restrict__ batch,
                         float* __restrict__ out) {
    const int lane = threadIdx.x & 63;
    const int wid  = threadIdx.x >> 6;
    const int gw   = blockIdx.x * 4 + wid;
    const int start = gw * 64;
    if (start >= NN) return;
    const int endn = (start + 64 < NN) ? start + 64 : NN;
    float acc = 0.f;
    int gcur = batch[start];
    for (int i = start; i < endn; ++i) {
        int g = batch[i];
        if (g != gcur) {
            atomicAdd(&out[gcur * DD + lane], acc);
            acc = 0.f;
            gcur = g;
        }
        acc += bf2f(h[(size_t)i * DD + lane]);
    }
    atomicAdd(&out[gcur * DD + lane], acc);
}

extern "C" void kernel_launch(void* const* d_in, const int* in_sizes, int n_in,
                              void* d_out, int out_size, void* d_ws, size_t ws_size,
                              hipStream_t stream) {
    const float* x     = (const float*)d_in[0];
    const int*   ei    = (const int*)d_in[1];
    const int*   batch = (const int*)d_in[2];
    const float* Wl[3] = {(const float*)d_in[3], (const float*)d_in[6], (const float*)d_in[9]};
    const float* bl[3] = {(const float*)d_in[4], (const float*)d_in[7], (const float*)d_in[10]};
    const float* Wr[3] = {(const float*)d_in[5], (const float*)d_in[8], (const float*)d_in[11]};
    float* out = (float*)d_out;

    char* ws = (char*)d_ws;
    size_t off = 0;
    auto alloc = [&](size_t bytes) -> void* {
        void* p = ws + off;
        off = (off + bytes + 255) & ~(size_t)255;
        return p;
    };
    int*   hist    = (int*)  alloc((size_t)NBUCK * NBLK * 4);
    int*   btot    = (int*)  alloc(((size_t)NBUCK + 1) * 4);
    float* deg_inv = (float*)alloc((size_t)NN * 4);
    int*   row_off = (int*)  alloc(((size_t)NN + 1) * 4);
    int*   srcs    = (int*)  alloc((size_t)NE * 4);
    u32*   part    = (u32*)  alloc((size_t)NE * 4);
    u16*   wbuf    = (u16*)  alloc((size_t)6 * 4096 * 2);
    u16*   xb      = (u16*)  alloc((size_t)NN * DD * 2);
    u16*   hAb     = (u16*)  alloc((size_t)NN * DD * 2);
    u16*   hBb     = (u16*)  alloc((size_t)NN * DD * 2);
    u8*    xb8     = (u8*)   alloc(((size_t)NN + 1) * DD);   // +1 sentinel row
    u8*    hA8     = (u8*)   alloc(((size_t)NN + 1) * DD);
    u8*    hB8     = (u8*)   alloc(((size_t)NN + 1) * DD);

    const int* e_src = ei;       // edge_index[0]
    const int* e_dst = ei + NE;  // edge_index[1]

    hipMemsetAsync(out, 0, (size_t)NG * DD * 4, stream);

    k_hist<<<NBLK, 256, 0, stream>>>(e_dst, hist);
    k_rowscan<<<NBUCK, 512, 0, stream>>>(hist, btot);
    k_btscan<<<1, 256, 0, stream>>>(btot);
    k_part<<<NBLK, 256, 0, stream>>>(e_src, e_dst, hist, btot, part);
    k_bucket<<<NBUCK, 512, 0, stream>>>(part, btot, row_off, srcs, deg_inv);
    k_cvtall<<<2048, 256, 0, stream>>>(x, xb, xb8, hA8, hB8,
                                       Wl[0], Wr[0], Wl[1], Wr[1], Wl[2], Wr[2], wbuf);

    // layer 1: gather fp8(x), x-term bf16(x) -> hAb (bf16) + hA8 (fp8)
    k_fused<<<NBT, 256, 0, stream>>>(xb,  xb8, hAb, hA8, wbuf,            bl[0], row_off, srcs, deg_inv, 1);
    // layer 2
    k_fused<<<NBT, 256, 0, stream>>>(hAb, hA8, hBb, hB8, wbuf + 1 * 8192, bl[1], row_off, srcs, deg_inv, 1);
    // layer 3 (fp8 output unused -> dump into xb8, which is dead)
    k_fused<<<NBT, 256, 0, stream>>>(hBb, hB8, hAb, xb8, wbuf + 2 * 8192, bl[2], row_off, srcs, deg_inv, 0);

    k_reduce<<<(NN / 64 + 4) / 4, 256, 0, stream>>>(hAb, batch, out);
}